// Round 1
// baseline (202.903 us; speedup 1.0000x reference)
//
#include <hip/hip_runtime.h>
#include <stdint.h>

constexpr int N_PTS = 8192;
constexpr int S_CTR = 2048;
constexpr int BATCH = 4;
constexpr int CHANS = 64;
constexpr int KS = 32;
constexpr int CH_OUT = CHANS + 3;   // 67
constexpr int M_PER_WAVE = 4;       // centers processed simultaneously per wave

// ---------------- Kernel 1: ball query ----------------
// Each wave handles M_PER_WAVE consecutive centers; lanes sweep the N points
// in chunks of 64. First-32-in-index-order collection via ballot+mbcnt
// compaction into LDS (matches reference sort(where(...))[:32] semantics).
__global__ __launch_bounds__(256) void bq_kernel(
    const float* __restrict__ xyz, const float* __restrict__ ctr,
    int* __restrict__ idx_out)
{
    const int wave = threadIdx.x >> 6;
    const int lane = threadIdx.x & 63;
    const int group = blockIdx.x * 4 + wave;       // wave-group id
    const int cg0 = group * M_PER_WAVE;            // first center (global) id
    const int b = cg0 >> 11;                       // / S_CTR (2048)
    const float* xb = xyz + (size_t)b * N_PTS * 3;

    float cx[M_PER_WAVE], cy[M_PER_WAVE], cz[M_PER_WAVE];
#pragma unroll
    for (int m = 0; m < M_PER_WAVE; ++m) {
        const float* c = ctr + (size_t)(cg0 + m) * 3;
        cx[m] = c[0]; cy[m] = c[1]; cz[m] = c[2];
    }

    __shared__ int lidx[4][M_PER_WAVE][KS];
    unsigned cnt[M_PER_WAVE];
#pragma unroll
    for (int m = 0; m < M_PER_WAVE; ++m) cnt[m] = 0;

    // threshold: python computes radius*radius in f64 then compares vs f32
    // -> f32(0.01) = 0.009999999776482582f  (NOT 0.1f*0.1f, one ulp higher)
    const float r2 = (float)(0.1 * 0.1);

    for (int n0 = 0; n0 < N_PTS; n0 += 64) {
        const int n = n0 + lane;
        const float* p = xb + n * 3;
        const float px = p[0], py = p[1], pz = p[2];
#pragma unroll
        for (int m = 0; m < M_PER_WAVE; ++m) {
            // exact non-fused f32 ops in XLA order: (dx^2 + dy^2) + dz^2
            const float dx = __fsub_rn(cx[m], px);
            const float dy = __fsub_rn(cy[m], py);
            const float dz = __fsub_rn(cz[m], pz);
            const float d2 = __fadd_rn(
                __fadd_rn(__fmul_rn(dx, dx), __fmul_rn(dy, dy)),
                __fmul_rn(dz, dz));
            const bool inb = d2 < r2;
            const unsigned long long mask = __ballot(inb);   // all 64 lanes active
            if (cnt[m] < (unsigned)KS) {                      // wave-uniform guard
                const unsigned rank = __builtin_amdgcn_mbcnt_hi(
                    (unsigned)(mask >> 32),
                    __builtin_amdgcn_mbcnt_lo((unsigned)mask, 0u));
                const unsigned slot = cnt[m] + rank;
                if (inb && slot < (unsigned)KS) lidx[wave][m][slot] = n;
                cnt[m] += (unsigned)__popcll(mask);
            }
        }
    }

    // Fill empty slots with first valid index (0 if none) and write out.
    // lane -> (half hh, slot k); static register indexing only (no dyn idx).
    const int k = lane & 31;
    const int hh = lane >> 5;
#pragma unroll
    for (int mj = 0; mj < M_PER_WAVE / 2; ++mj) {
        const int m = mj * 2 + hh;
        const unsigned c = hh ? cnt[mj * 2 + 1] : cnt[mj * 2];
        const int first = (c > 0) ? lidx[wave][m][0] : 0;
        const int v = (k < (int)c) ? lidx[wave][m][k] : first;
        idx_out[(size_t)(cg0 + m) * KS + k] = v;
    }
}

// ---------------- Kernel 2: gather + concat ----------------
// One wave per center. lane = (half, k). Per iteration the wave writes two
// channels: two contiguous 128B segments. Feature reads are scattered dwords
// but features (2MB/batch) are L2-resident.
__global__ __launch_bounds__(256) void gather_kernel(
    const float* __restrict__ xyz, const float* __restrict__ ctr,
    const float* __restrict__ feat, const int* __restrict__ idx_ws,
    float* __restrict__ out)
{
    const int wave = threadIdx.x >> 6;
    const int lane = threadIdx.x & 63;
    const int cg = blockIdx.x * 4 + wave;          // 0..B*S-1
    const int b = cg >> 11;
    const int s = cg & (S_CTR - 1);
    const int k = lane & 31;
    const int half = lane >> 5;

    const int id = idx_ws[(size_t)cg * KS + k];

    const float* pp = xyz + ((size_t)b * N_PTS + id) * 3;
    const float* cc = ctr + (size_t)cg * 3;
    const float g0 = pp[0] - cc[0];
    const float g1 = pp[1] - cc[1];
    const float g2 = pp[2] - cc[2];

    const float* fb = feat + (size_t)b * CHANS * N_PTS + id;
    float* ob = out + ((size_t)b * CH_OUT * S_CTR + s) * KS + k;
    const size_t chs = (size_t)S_CTR * KS;

#pragma unroll
    for (int ch0 = 0; ch0 < CH_OUT; ch0 += 2) {
        const int ch = ch0 + half;
        if (ch < CH_OUT) {
            float v;
            if (ch0 == 0) {                 // ch = 0 or 1 : xyz channels
                v = half ? g1 : g0;
            } else if (ch0 == 2) {          // half0: xyz z ; half1: feature ch 0
                v = half ? fb[0] : g2;
            } else {                        // feature channels
                v = fb[(size_t)(ch - 3) * N_PTS];
            }
            ob[(size_t)ch * chs] = v;
        }
    }
}

extern "C" void kernel_launch(void* const* d_in, const int* in_sizes, int n_in,
                              void* d_out, int out_size, void* d_ws, size_t ws_size,
                              hipStream_t stream)
{
    const float* xyz  = (const float*)d_in[0];   // (B,N,3) f32
    const float* ctr  = (const float*)d_in[1];   // (B,S,3) f32
    const float* feat = (const float*)d_in[2];   // (B,C,N) f32
    float* out = (float*)d_out;                  // (B,67,S,K) f32
    int* idx_ws = (int*)d_ws;                    // B*S*K ints = 1 MB

    const int n_groups = BATCH * S_CTR / M_PER_WAVE;           // 2048 wave-groups
    bq_kernel<<<dim3(n_groups / 4), dim3(256), 0, stream>>>(xyz, ctr, idx_ws);

    gather_kernel<<<dim3(BATCH * S_CTR / 4), dim3(256), 0, stream>>>(
        xyz, ctr, feat, idx_ws, out);
}

// Round 2
// 123.122 us; speedup vs baseline: 1.6480x; 1.6480x over previous
//
#include <hip/hip_runtime.h>
#include <stdint.h>

constexpr int N_PTS = 8192;
constexpr int S_CTR = 2048;
constexpr int BATCH = 4;
constexpr int CHANS = 64;
constexpr int KS = 32;
constexpr int CH_OUT = CHANS + 3;   // 67
constexpr int M = 2;                // centers per wave
constexpr int STAGE = 512;          // points per stage group
constexpr int NSG = N_PTS / STAGE;  // 16

// ---------------- Kernel 1: ball query ----------------
// Block = 256 threads = 4 waves, M=2 centers/wave -> 8 centers/block.
// Points double-buffer-staged into LDS (whole block shares), ballot+mbcnt
// first-32-in-index-order compaction (matches sort(where(...))[:32]).
__global__ __launch_bounds__(256) void bq_kernel(
    const float* __restrict__ xyz, const float* __restrict__ ctr,
    int* __restrict__ idx_out)
{
    __shared__ float pts[2][STAGE * 3];     // 2 x 6KB
    __shared__ int lidx[4][M][KS];          // 1KB
    const int t = threadIdx.x;
    const int wave = t >> 6, lane = t & 63;
    const int cg0 = blockIdx.x * (4 * M) + wave * M;  // first center of wave
    const int b = cg0 >> 11;                // /2048; block spans 8 centers, same batch
    const float* xb = xyz + (size_t)b * N_PTS * 3;

    float cx[M], cy[M], cz[M];
#pragma unroll
    for (int m = 0; m < M; ++m) {
        const float* c = ctr + (size_t)(cg0 + m) * 3;
        cx[m] = c[0]; cy[m] = c[1]; cz[m] = c[2];
    }
    unsigned cnt[M];
#pragma unroll
    for (int m = 0; m < M; ++m) cnt[m] = 0;

    // f32(0.1*0.1 in f64) — one ulp below 0.1f*0.1f; verified absmax==0.
    const float r2 = (float)(0.1 * 0.1);

    // stage group 0 (coalesced dword copy, linear LDS -> 2-way max, free)
#pragma unroll
    for (int j = 0; j < 6; ++j)
        pts[0][t + j * 256] = xb[t + j * 256];
    __syncthreads();

    for (int sg = 0; sg < NSG; ++sg) {
        const int cur = sg & 1;
        if (sg + 1 < NSG) {
            const float* src = xb + (size_t)(sg + 1) * STAGE * 3;
#pragma unroll
            for (int j = 0; j < 6; ++j)
                pts[cur ^ 1][t + j * 256] = src[t + j * 256];
        }
        if (cnt[0] < (unsigned)KS || cnt[1] < (unsigned)KS) {  // wave-uniform
            for (int c8 = 0; c8 < STAGE / 64; ++c8) {
                const int pbase = (c8 * 64 + lane) * 3;
                const float px = pts[cur][pbase + 0];
                const float py = pts[cur][pbase + 1];
                const float pz = pts[cur][pbase + 2];
                const int n = sg * STAGE + c8 * 64 + lane;
#pragma unroll
                for (int m = 0; m < M; ++m) {
                    // exact non-fused f32, XLA order: (dx^2 + dy^2) + dz^2
                    const float dx = __fsub_rn(cx[m], px);
                    const float dy = __fsub_rn(cy[m], py);
                    const float dz = __fsub_rn(cz[m], pz);
                    const float d2 = __fadd_rn(
                        __fadd_rn(__fmul_rn(dx, dx), __fmul_rn(dy, dy)),
                        __fmul_rn(dz, dz));
                    const bool inb = d2 < r2;
                    const unsigned long long mask = __ballot(inb);
                    // skip append machinery when no hits (common) or full
                    if (mask != 0ull && cnt[m] < (unsigned)KS) {
                        const unsigned rank = __builtin_amdgcn_mbcnt_hi(
                            (unsigned)(mask >> 32),
                            __builtin_amdgcn_mbcnt_lo((unsigned)mask, 0u));
                        const unsigned slot = cnt[m] + rank;
                        if (inb && slot < (unsigned)KS) lidx[wave][m][slot] = n;
                        cnt[m] += (unsigned)__popcll(mask);
                    }
                }
            }
        }
        __syncthreads();
    }

    // lane -> (half hh = which center, slot k); no dynamic register indexing
    const int k = lane & 31;
    const int hh = lane >> 5;
    const unsigned c = hh ? cnt[1] : cnt[0];
    const int first = (c > 0) ? lidx[wave][hh][0] : 0;
    const int v = (k < (int)c) ? lidx[wave][hh][k] : first;
    idx_out[(size_t)(cg0 + hh) * KS + k] = v;
}

// ---------------- Kernel 2: feature transpose (B,C,N) -> (B,N,C) ----------------
__global__ __launch_bounds__(256) void transpose_kernel(
    const float* __restrict__ feat, float* __restrict__ featT)
{
    __shared__ float tile[64][65];
    const int t = threadIdx.x;
    const int n0 = blockIdx.x * 64;
    const int b = blockIdx.y;
    const float* fb = feat + (size_t)b * CHANS * N_PTS;
#pragma unroll
    for (int r = 0; r < 16; ++r) {
        const int c = r * 4 + (t >> 6);
        tile[c][t & 63] = fb[(size_t)c * N_PTS + n0 + (t & 63)];
    }
    __syncthreads();
    float* ob = featT + ((size_t)b * N_PTS + n0) * CHANS;
#pragma unroll
    for (int r = 0; r < 16; ++r) {
        const int n = r * 4 + (t >> 6);
        // read tile[c][n], c = lane: stride 65 dwords -> 2-way max, free
        ob[(size_t)n * CHANS + (t & 63)] = tile[t & 63][n];
    }
}

// ---------------- Kernel 3: gather + concat (transposed features) ----------------
// thread = (center, k). Reads its point's 64 channels contiguously (4x float4,
// full 64B-line utilization), writes 67 dword stores, each lane-contiguous.
__global__ __launch_bounds__(256) void gather_kernel(
    const float* __restrict__ xyz, const float* __restrict__ ctr,
    const float* __restrict__ featT, const int* __restrict__ idx_ws,
    float* __restrict__ out)
{
    const int tg = blockIdx.x * 256 + threadIdx.x;
    const int cg = tg >> 5;                 // center 0..8191
    const int k = tg & 31;
    const int b = cg >> 11;
    const int s = cg & (S_CTR - 1);
    const int id = idx_ws[(size_t)cg * KS + k];

    const float* pp = xyz + ((size_t)b * N_PTS + id) * 3;
    const float* cc = ctr + (size_t)cg * 3;
    const float g0 = __fsub_rn(pp[0], cc[0]);
    const float g1 = __fsub_rn(pp[1], cc[1]);
    const float g2 = __fsub_rn(pp[2], cc[2]);

    float f[CHANS];
    const float4* fr =
        (const float4*)(featT + ((size_t)b * N_PTS + id) * CHANS);
#pragma unroll
    for (int j = 0; j < CHANS / 4; ++j) {
        const float4 v = fr[j];
        f[j * 4 + 0] = v.x; f[j * 4 + 1] = v.y;
        f[j * 4 + 2] = v.z; f[j * 4 + 3] = v.w;
    }

    float* ob = out + ((size_t)b * CH_OUT * S_CTR + s) * KS + k;
    const size_t chs = (size_t)S_CTR * KS;
    ob[0] = g0;
    ob[chs] = g1;
    ob[2 * chs] = g2;
#pragma unroll
    for (int ch = 0; ch < CHANS; ++ch)
        ob[(size_t)(ch + 3) * chs] = f[ch];
}

// ---------------- Fallback gather (no transpose; if ws too small) ----------------
__global__ __launch_bounds__(256) void gather_direct(
    const float* __restrict__ xyz, const float* __restrict__ ctr,
    const float* __restrict__ feat, const int* __restrict__ idx_ws,
    float* __restrict__ out)
{
    const int wave = threadIdx.x >> 6;
    const int lane = threadIdx.x & 63;
    const int cg = blockIdx.x * 4 + wave;
    const int b = cg >> 11;
    const int s = cg & (S_CTR - 1);
    const int k = lane & 31;
    const int half = lane >> 5;

    const int id = idx_ws[(size_t)cg * KS + k];
    const float* pp = xyz + ((size_t)b * N_PTS + id) * 3;
    const float* cc = ctr + (size_t)cg * 3;
    const float g0 = __fsub_rn(pp[0], cc[0]);
    const float g1 = __fsub_rn(pp[1], cc[1]);
    const float g2 = __fsub_rn(pp[2], cc[2]);

    const float* fb = feat + (size_t)b * CHANS * N_PTS + id;
    float* ob = out + ((size_t)b * CH_OUT * S_CTR + s) * KS + k;
    const size_t chs = (size_t)S_CTR * KS;

#pragma unroll
    for (int ch0 = 0; ch0 < CH_OUT; ch0 += 2) {
        const int ch = ch0 + half;
        if (ch < CH_OUT) {
            float v;
            if (ch0 == 0)      v = half ? g1 : g0;
            else if (ch0 == 2) v = half ? fb[0] : g2;
            else               v = fb[(size_t)(ch - 3) * N_PTS];
            ob[(size_t)ch * chs] = v;
        }
    }
}

extern "C" void kernel_launch(void* const* d_in, const int* in_sizes, int n_in,
                              void* d_out, int out_size, void* d_ws, size_t ws_size,
                              hipStream_t stream)
{
    const float* xyz  = (const float*)d_in[0];   // (B,N,3) f32
    const float* ctr  = (const float*)d_in[1];   // (B,S,3) f32
    const float* feat = (const float*)d_in[2];   // (B,C,N) f32
    float* out = (float*)d_out;                  // (B,67,S,K) f32

    const size_t idx_bytes = (size_t)BATCH * S_CTR * KS * sizeof(int);       // 1 MB
    const size_t featT_bytes = (size_t)BATCH * N_PTS * CHANS * sizeof(float); // 8 MB
    int* idx_ws = (int*)d_ws;

    // ball query: 1024 blocks x 256 threads = 4096 waves (16/CU)
    bq_kernel<<<dim3(BATCH * S_CTR / (4 * M)), dim3(256), 0, stream>>>(
        xyz, ctr, idx_ws);

    if (ws_size >= idx_bytes + featT_bytes) {
        float* featT = (float*)((char*)d_ws + idx_bytes);
        transpose_kernel<<<dim3(N_PTS / 64, BATCH), dim3(256), 0, stream>>>(
            feat, featT);
        gather_kernel<<<dim3(BATCH * S_CTR * KS / 256), dim3(256), 0, stream>>>(
            xyz, ctr, featT, idx_ws, out);
    } else {
        gather_direct<<<dim3(BATCH * S_CTR / 4), dim3(256), 0, stream>>>(
            xyz, ctr, feat, idx_ws, out);
    }
}